// Round 1
// baseline (208.942 us; speedup 1.0000x reference)
//
#include <hip/hip_runtime.h>

#define N_ROWS 8192
#define DIM    128
#define BM     128
#define BK     32
#define LDSPAD 4
#define LDB    (BM + LDSPAD)   // 132 floats; 528B row stride keeps float4 alignment

// Each block computes a 128x128 tile of the pairwise-distance matrix (upper
// triangle only, bi <= bj), weights each distance by +1 (same class) or
// -0.5 (cross class), and atomically accumulates a per-block double partial.
__global__ __launch_bounds__(256)
void pairsum_kernel(const float* __restrict__ X,
                    const int* __restrict__ Y,
                    double* __restrict__ gsum)
{
    const int bj = blockIdx.x;
    const int bi = blockIdx.y;
    if (bi > bj) return;   // triangle: only bi <= bj blocks do work

    const int tid = threadIdx.x;
    const int i0 = bi * BM;
    const int j0 = bj * BM;

    __shared__ float As[BK][LDB];
    __shared__ float Bs[BK][LDB];
    __shared__ float nI[BM];
    __shared__ float nJ[BM];
    __shared__ int   yI[BM];
    __shared__ int   yJ[BM];
    __shared__ double wsum[4];

    // --- per-row squared norms + labels: 256 threads -> 128 i-rows + 128 j-rows
    {
        const int  r   = tid & (BM - 1);
        const bool isJ = tid >= BM;
        const int  row = (isJ ? j0 : i0) + r;
        const float4* p = (const float4*)(X + (size_t)row * DIM);
        float s = 0.f;
        #pragma unroll
        for (int q = 0; q < DIM / 4; ++q) {
            float4 v = p[q];
            s = fmaf(v.x, v.x, s);
            s = fmaf(v.y, v.y, s);
            s = fmaf(v.z, v.z, s);
            s = fmaf(v.w, v.w, s);
        }
        if (isJ) { nJ[r] = s; yJ[r] = Y[row]; }
        else     { nI[r] = s; yI[r] = Y[row]; }
    }

    float dot[8][8];
    #pragma unroll
    for (int m = 0; m < 8; ++m)
        #pragma unroll
        for (int n = 0; n < 8; ++n)
            dot[m][n] = 0.f;

    const int tx = tid & 15;   // 16 cols of threads -> 8 j-rows each
    const int ty = tid >> 4;   // 16 rows of threads -> 8 i-rows each

    for (int kc = 0; kc < DIM; kc += BK) {
        __syncthreads();   // protect LDS from previous iteration's readers
        // stage A/B chunks k-major: As[k][row]; 1024 float4 slots per matrix
        #pragma unroll
        for (int p = 0; p < 4; ++p) {
            const int s   = p * 256 + tid;
            const int row = s >> 3;   // 0..127
            const int kg  = s & 7;    // float4 index within BK=32 chunk
            const float4 va = *(const float4*)(X + (size_t)(i0 + row) * DIM + kc + kg * 4);
            const float4 vb = *(const float4*)(X + (size_t)(j0 + row) * DIM + kc + kg * 4);
            As[kg*4+0][row] = va.x; As[kg*4+1][row] = va.y;
            As[kg*4+2][row] = va.z; As[kg*4+3][row] = va.w;
            Bs[kg*4+0][row] = vb.x; Bs[kg*4+1][row] = vb.y;
            Bs[kg*4+2][row] = vb.z; Bs[kg*4+3][row] = vb.w;
        }
        __syncthreads();
        #pragma unroll
        for (int k = 0; k < BK; ++k) {
            float a[8], b[8];
            *(float4*)&a[0] = *(const float4*)&As[k][ty*8];
            *(float4*)&a[4] = *(const float4*)&As[k][ty*8+4];
            *(float4*)&b[0] = *(const float4*)&Bs[k][tx*8];
            *(float4*)&b[4] = *(const float4*)&Bs[k][tx*8+4];
            #pragma unroll
            for (int m = 0; m < 8; ++m)
                #pragma unroll
                for (int n = 0; n < 8; ++n)
                    dot[m][n] = fmaf(a[m], b[n], dot[m][n]);
        }
    }

    // --- epilogue: distance + weight, masked to strict upper triangle gi < gj
    float s = 0.f;
    const int ib = ty * 8, jb = tx * 8;
    #pragma unroll
    for (int m = 0; m < 8; ++m) {
        const int   gi = i0 + ib + m;
        const float ni = nI[ib + m];
        const int   yi = yI[ib + m];
        #pragma unroll
        for (int n = 0; n < 8; ++n) {
            const int gj = j0 + jb + n;
            float sq = fmaf(-2.f, dot[m][n], ni + nJ[jb + n]);
            sq = fmaxf(sq, 0.f);
            const float d = __builtin_amdgcn_sqrtf(sq);
            const float w = (yi == yJ[jb + n]) ? 1.0f : -0.5f;
            if (gi < gj) s = fmaf(w, d, s);
        }
    }

    // --- block reduction: wave shuffle (64-wide) -> LDS doubles -> atomic
    #pragma unroll
    for (int off = 32; off > 0; off >>= 1)
        s += __shfl_down(s, off);

    const int lane = tid & 63;
    const int wid  = tid >> 6;
    if (lane == 0) wsum[wid] = (double)s;
    __syncthreads();
    if (tid == 0)
        atomicAdd(gsum, wsum[0] + wsum[1] + wsum[2] + wsum[3]);
}

__global__ void finalize_kernel(const double* __restrict__ gsum, float* __restrict__ out)
{
    out[0] = (float)(2.0 * gsum[0]);   // ordered pairs = 2 x strict upper triangle
}

extern "C" void kernel_launch(void* const* d_in, const int* in_sizes, int n_in,
                              void* d_out, int out_size, void* d_ws, size_t ws_size,
                              hipStream_t stream)
{
    const float* X = (const float*)d_in[0];
    const int*   Y = (const int*)d_in[1];
    float*  out  = (float*)d_out;
    double* gsum = (double*)d_ws;

    hipMemsetAsync(d_ws, 0, sizeof(double), stream);  // ws is re-poisoned to 0xAA

    dim3 grid(N_ROWS / BM, N_ROWS / BM);
    pairsum_kernel<<<grid, 256, 0, stream>>>(X, Y, gsum);
    finalize_kernel<<<1, 1, 0, stream>>>(gsum, out);
}

// Round 4
// 118.435 us; speedup vs baseline: 1.7642x; 1.7642x over previous
//
#include <hip/hip_runtime.h>

#define N_ROWS 8192
#define DIM    128
#define BM     128
#define BK     64
#define NBLK   (N_ROWS / BM)          // 64
#define NTRI   (NBLK * (NBLK + 1) / 2) // 2080

typedef _Float16 half4 __attribute__((ext_vector_type(4)));
typedef _Float16 half8 __attribute__((ext_vector_type(8)));
typedef float    f32x16 __attribute__((ext_vector_type(16)));

// ---------------------------------------------------------------------------
// Prep: X (fp32) -> Xhi + Xlo (fp16 split, x = hi + lo exactly in fp32) and
// per-row squared norms. One thread per float4 (32 float4 per row).
__global__ __launch_bounds__(256)
void prep_kernel(const float* __restrict__ X,
                 _Float16* __restrict__ Xhi, _Float16* __restrict__ Xlo,
                 float* __restrict__ norms)
{
    const int g = blockIdx.x * 256 + threadIdx.x;    // float4 index
    const float4 v = ((const float4*)X)[g];
    half4 h, l;
    h.x = (_Float16)v.x; l.x = (_Float16)(v.x - (float)h.x);
    h.y = (_Float16)v.y; l.y = (_Float16)(v.y - (float)h.y);
    h.z = (_Float16)v.z; l.z = (_Float16)(v.z - (float)h.z);
    h.w = (_Float16)v.w; l.w = (_Float16)(v.w - (float)h.w);
    *(half4*)(Xhi + (size_t)g * 4) = h;
    *(half4*)(Xlo + (size_t)g * 4) = l;

    float s = fmaf(v.x, v.x, fmaf(v.y, v.y, fmaf(v.z, v.z, v.w * v.w)));
    #pragma unroll
    for (int off = 1; off <= 16; off <<= 1) s += __shfl_xor(s, off);
    if ((threadIdx.x & 31) == 0) norms[g >> 5] = s;   // 32 float4 per row
}

// ---------------------------------------------------------------------------
// Main: one block per upper-triangle 128x128 tile. Split-fp16 MFMA dots,
// distance + class-weight epilogue, double-atomic partial sum.
__global__ __launch_bounds__(256)
void pairsum_mfma(const _Float16* __restrict__ Xhi, const _Float16* __restrict__ Xlo,
                  const float* __restrict__ norms, const int* __restrict__ Y,
                  double* __restrict__ gsum)
{
    // triangular decode: cum(b) = b*(129-b)/2
    const int kb = blockIdx.x;
    int bi = (int)((129.0f - sqrtf(fmaf(-8.0f, (float)kb, 129.0f * 129.0f))) * 0.5f);
    while ((bi + 1) * (129 - (bi + 1)) / 2 <= kb) ++bi;
    while (bi * (129 - bi) / 2 > kb) --bi;
    const int bj = bi + (kb - bi * (129 - bi) / 2);
    const int i0 = bi * BM, j0 = bj * BM;

    const int tid  = threadIdx.x;
    const int lane = tid & 63;
    const int w    = tid >> 6;        // wave 0..3
    const int wy   = w >> 1;          // 2x2 wave grid, 64x64 each
    const int wx   = w & 1;
    const int lr   = lane & 31;       // row/col within 32x32 MFMA tile
    const int lh   = lane >> 5;       // k-half selector

    // LDS: 4 x 128x64 fp16 tiles (XOR-swizzled rows), 64KB
    __shared__ __align__(16) char tile[65536];
    const int AH = 0, AL = 16384, BH = 32768, BL = 49152;
    __shared__ float nI[BM], nJ[BM];
    __shared__ int   yI[BM], yJ[BM];
    __shared__ double wsum[4];

    if (tid < BM) { nI[tid] = norms[i0 + tid]; yI[tid] = Y[i0 + tid]; }
    else { const int r = tid & (BM - 1); nJ[r] = norms[j0 + r]; yJ[r] = Y[j0 + r]; }

    f32x16 acc[2][2];
    #pragma unroll
    for (int m = 0; m < 2; ++m)
        #pragma unroll
        for (int n = 0; n < 2; ++n)
            #pragma unroll
            for (int r = 0; r < 16; ++r)
                acc[m][n][r] = 0.0f;

    #pragma unroll
    for (int c = 0; c < 2; ++c) {
        const int kc = c * BK;
        __syncthreads();   // LDS safe to overwrite
        // stage: 1024 x 16B per array; thread handles 4 groups per array
        #pragma unroll
        for (int p = 0; p < 4; ++p) {
            const int g2  = p * 256 + tid;
            const int row = g2 >> 3;            // 0..127
            const int kk  = g2 & 7;             // 16B group within row-chunk
            const int off = row * 128 + (((kk ^ (row & 7)) << 4));
            const size_t ga = (size_t)(i0 + row) * DIM + kc + kk * 8;
            const size_t gb = (size_t)(j0 + row) * DIM + kc + kk * 8;
            *(half8*)(tile + AH + off) = *(const half8*)(Xhi + ga);
            *(half8*)(tile + AL + off) = *(const half8*)(Xlo + ga);
            *(half8*)(tile + BH + off) = *(const half8*)(Xhi + gb);
            *(half8*)(tile + BL + off) = *(const half8*)(Xlo + gb);
        }
        __syncthreads();
        #pragma unroll
        for (int ks = 0; ks < 4; ++ks) {
            const int kk16 = ks * 2 + lh;       // 16B group index 0..7
            half8 ah[2], al[2], bh[2], bl[2];
            #pragma unroll
            for (int m = 0; m < 2; ++m) {
                const int ar = wy * 64 + m * 32 + lr;
                const int ao = ar * 128 + (((kk16 ^ (ar & 7)) << 4));
                ah[m] = *(const half8*)(tile + AH + ao);
                al[m] = *(const half8*)(tile + AL + ao);
                const int br = wx * 64 + m * 32 + lr;
                const int bo = br * 128 + (((kk16 ^ (br & 7)) << 4));
                bh[m] = *(const half8*)(tile + BH + bo);
                bl[m] = *(const half8*)(tile + BL + bo);
            }
            #pragma unroll
            for (int m = 0; m < 2; ++m)
                #pragma unroll
                for (int n = 0; n < 2; ++n) {
                    acc[m][n] = __builtin_amdgcn_mfma_f32_32x32x16_f16(ah[m], bh[n], acc[m][n], 0, 0, 0);
                    acc[m][n] = __builtin_amdgcn_mfma_f32_32x32x16_f16(ah[m], bl[n], acc[m][n], 0, 0, 0);
                    acc[m][n] = __builtin_amdgcn_mfma_f32_32x32x16_f16(al[m], bh[n], acc[m][n], 0, 0, 0);
                }
        }
    }

    // epilogue: C/D map col=lane&31, row=(reg&3)+8*(reg>>2)+4*(lane>>5)
    float s = 0.0f;
    float nJv[2]; int yJv[2];
    #pragma unroll
    for (int n = 0; n < 2; ++n) {
        const int lj = wx * 64 + n * 32 + lr;
        nJv[n] = nJ[lj]; yJv[n] = yJ[lj];
    }
    #pragma unroll
    for (int m = 0; m < 2; ++m) {
        #pragma unroll
        for (int r = 0; r < 16; ++r) {
            const int rowin = (r & 3) + 8 * (r >> 2) + 4 * lh;
            const int li = wy * 64 + m * 32 + rowin;
            const float ni = nI[li];
            const int   yi = yI[li];
            const int   gi = i0 + li;
            #pragma unroll
            for (int n = 0; n < 2; ++n) {
                const int gj = j0 + wx * 64 + n * 32 + lr;
                float sq = fmaf(-2.0f, acc[m][n][r], ni + nJv[n]);
                sq = fmaxf(sq, 0.0f);
                const float d = __builtin_amdgcn_sqrtf(sq);
                if (gi < gj) s = fmaf((yi == yJv[n]) ? 1.0f : -0.5f, d, s);
            }
        }
    }

    #pragma unroll
    for (int off = 32; off > 0; off >>= 1) s += __shfl_down(s, off);
    if (lane == 0) wsum[w] = (double)s;
    __syncthreads();
    if (tid == 0) atomicAdd(gsum, wsum[0] + wsum[1] + wsum[2] + wsum[3]);
}

__global__ void finalize_kernel(const double* __restrict__ gsum, float* __restrict__ out)
{
    out[0] = (float)(2.0 * gsum[0]);
}

// ---------------------------------------------------------------------------
// Fallback (ws too small): round-1 VALU kernel, known-correct.
#define LDSPAD 4
#define LDB (BM + LDSPAD)
__global__ __launch_bounds__(256)
void pairsum_valu(const float* __restrict__ X, const int* __restrict__ Y,
                  double* __restrict__ gsum)
{
    const int bj = blockIdx.x, bi = blockIdx.y;
    if (bi > bj) return;
    const int tid = threadIdx.x;
    const int i0 = bi * BM, j0 = bj * BM;
    __shared__ float As[32][LDB], Bs[32][LDB];
    __shared__ float nI[BM], nJ[BM];
    __shared__ int yI[BM], yJ[BM];
    __shared__ double wsum[4];
    {
        const int r = tid & (BM - 1);
        const bool isJ = tid >= BM;
        const int row = (isJ ? j0 : i0) + r;
        const float4* p = (const float4*)(X + (size_t)row * DIM);
        float s = 0.f;
        #pragma unroll
        for (int q = 0; q < DIM / 4; ++q) {
            float4 v = p[q];
            s = fmaf(v.x, v.x, s); s = fmaf(v.y, v.y, s);
            s = fmaf(v.z, v.z, s); s = fmaf(v.w, v.w, s);
        }
        if (isJ) { nJ[r] = s; yJ[r] = Y[row]; }
        else     { nI[r] = s; yI[r] = Y[row]; }
    }
    float dot[8][8];
    #pragma unroll
    for (int m = 0; m < 8; ++m)
        #pragma unroll
        for (int n = 0; n < 8; ++n) dot[m][n] = 0.f;
    const int tx = tid & 15, ty = tid >> 4;
    for (int kc = 0; kc < DIM; kc += 32) {
        __syncthreads();
        #pragma unroll
        for (int p = 0; p < 4; ++p) {
            const int s2 = p * 256 + tid;
            const int row = s2 >> 3, kg = s2 & 7;
            const float4 va = *(const float4*)(X + (size_t)(i0 + row) * DIM + kc + kg * 4);
            const float4 vb = *(const float4*)(X + (size_t)(j0 + row) * DIM + kc + kg * 4);
            As[kg*4+0][row] = va.x; As[kg*4+1][row] = va.y;
            As[kg*4+2][row] = va.z; As[kg*4+3][row] = va.w;
            Bs[kg*4+0][row] = vb.x; Bs[kg*4+1][row] = vb.y;
            Bs[kg*4+2][row] = vb.z; Bs[kg*4+3][row] = vb.w;
        }
        __syncthreads();
        #pragma unroll
        for (int k = 0; k < 32; ++k) {
            float a[8], b[8];
            *(float4*)&a[0] = *(const float4*)&As[k][ty*8];
            *(float4*)&a[4] = *(const float4*)&As[k][ty*8+4];
            *(float4*)&b[0] = *(const float4*)&Bs[k][tx*8];
            *(float4*)&b[4] = *(const float4*)&Bs[k][tx*8+4];
            #pragma unroll
            for (int m = 0; m < 8; ++m)
                #pragma unroll
                for (int n = 0; n < 8; ++n)
                    dot[m][n] = fmaf(a[m], b[n], dot[m][n]);
        }
    }
    float s = 0.f;
    const int ib = ty * 8, jb = tx * 8;
    #pragma unroll
    for (int m = 0; m < 8; ++m) {
        const int gi = i0 + ib + m;
        const float ni = nI[ib + m];
        const int yi = yI[ib + m];
        #pragma unroll
        for (int n = 0; n < 8; ++n) {
            const int gj = j0 + jb + n;
            float sq = fmaf(-2.f, dot[m][n], ni + nJ[jb + n]);
            sq = fmaxf(sq, 0.f);
            const float d = __builtin_amdgcn_sqrtf(sq);
            if (gi < gj) s = fmaf((yi == yJ[jb + n]) ? 1.0f : -0.5f, d, s);
        }
    }
    #pragma unroll
    for (int off = 32; off > 0; off >>= 1) s += __shfl_down(s, off);
    const int lane = tid & 63, wid = tid >> 6;
    if (lane == 0) wsum[wid] = (double)s;
    __syncthreads();
    if (tid == 0) atomicAdd(gsum, wsum[0] + wsum[1] + wsum[2] + wsum[3]);
}

// ---------------------------------------------------------------------------
extern "C" void kernel_launch(void* const* d_in, const int* in_sizes, int n_in,
                              void* d_out, int out_size, void* d_ws, size_t ws_size,
                              hipStream_t stream)
{
    const float* X = (const float*)d_in[0];
    const int*   Y = (const int*)d_in[1];
    float* out = (float*)d_out;

    // ws layout: [0] double gsum | 64: norms (32KB) | Xhi (2MB) | Xlo (2MB)
    const size_t OFF_NORM = 64;
    const size_t OFF_XHI  = OFF_NORM + (size_t)N_ROWS * 4;
    const size_t OFF_XLO  = OFF_XHI + (size_t)N_ROWS * DIM * 2;
    const size_t REQ      = OFF_XLO + (size_t)N_ROWS * DIM * 2;

    double* gsum = (double*)d_ws;
    hipMemsetAsync(d_ws, 0, sizeof(double), stream);

    if (ws_size >= REQ) {
        float*     norms = (float*)((char*)d_ws + OFF_NORM);
        _Float16*  Xhi   = (_Float16*)((char*)d_ws + OFF_XHI);
        _Float16*  Xlo   = (_Float16*)((char*)d_ws + OFF_XLO);
        prep_kernel<<<(N_ROWS * DIM / 4) / 256, 256, 0, stream>>>(X, Xhi, Xlo, norms);
        pairsum_mfma<<<NTRI, 256, 0, stream>>>(Xhi, Xlo, norms, Y, gsum);
    } else {
        dim3 grid(NBLK, NBLK);
        pairsum_valu<<<grid, 256, 0, stream>>>(X, Y, gsum);
    }
    finalize_kernel<<<1, 1, 0, stream>>>(gsum, out);
}

// Round 6
// 105.488 us; speedup vs baseline: 1.9807x; 1.1227x over previous
//
#include <hip/hip_runtime.h>

#define N_ROWS 8192
#define DIM    128
#define BM     128
#define NBLK   (N_ROWS / BM)           // 64
#define NTRI   (NBLK * (NBLK + 1) / 2) // 2080

// tiled blob geometry: per row-block 64KB = 4 phases x (128 rows x 128B)
// row layout per phase: 8 x 16B groups; g<4 = hi(k=g*8..+8), g>=4 = lo;
// stored at group slot (g ^ (row&7))  [XOR swizzle baked into global layout]
#define BLOB_PER_RB   65536
#define BLOB_PER_PH   16384

typedef _Float16 half8 __attribute__((ext_vector_type(8)));
typedef float    f32x16 __attribute__((ext_vector_type(16)));

typedef const __attribute__((address_space(1))) unsigned int glb_uint;
typedef __attribute__((address_space(3))) unsigned int lds_uint;

// addrspace casts THROUGH uintptr_t (CK pattern): generic->int->AS-ptr is
// always legal; truncation to 32b drops the LDS aperture bits correctly.
__device__ inline void gload_lds16(const void* g, void* l)
{
    __builtin_amdgcn_global_load_lds((glb_uint*)(uintptr_t)g,
                                     (lds_uint*)(uintptr_t)l, 16, 0, 0);
}

// ---------------------------------------------------------------------------
// Prep: X fp32 -> pre-tiled, pre-swizzled fp16 split blob + row norms.
// One thread per (row, phase, gg): 8 floats -> hi8 + lo8 groups.
__global__ __launch_bounds__(256)
void prep_tiled(const float* __restrict__ X, char* __restrict__ blob,
                float* __restrict__ norms)
{
    const int t   = blockIdx.x * 256 + threadIdx.x;  // 0 .. 131071
    const int gg  = t & 3;
    const int p   = (t >> 2) & 3;
    const int row = t >> 4;

    const float4* src = (const float4*)(X + (size_t)row * DIM + p * 32 + gg * 8);
    const float4 v0 = src[0], v1 = src[1];
    const float xs[8] = {v0.x, v0.y, v0.z, v0.w, v1.x, v1.y, v1.z, v1.w};

    half8 h, l;
    float ns = 0.0f;
    #pragma unroll
    for (int i = 0; i < 8; ++i) {
        const float x = xs[i];
        const _Float16 hh = (_Float16)x;
        h[i] = hh;
        l[i] = (_Float16)(x - (float)hh);
        ns = fmaf(x, x, ns);
    }

    const int rb = row >> 7, r = row & 127;
    char* base = blob + (size_t)rb * BLOB_PER_RB + p * BLOB_PER_PH + r * 128;
    *(half8*)(base + (((gg    ) ^ (r & 7)) << 4)) = h;
    *(half8*)(base + (((gg + 4) ^ (r & 7)) << 4)) = l;

    // 16 consecutive threads cover one row (4 phases x 4 groups)
    #pragma unroll
    for (int off = 1; off <= 8; off <<= 1) ns += __shfl_xor(ns, off);
    if ((t & 15) == 0) norms[row] = ns;
}

// ---------------------------------------------------------------------------
// Main: one block per upper-triangle 128x128 tile. global_load_lds staging
// from the pre-swizzled blob, depth-2 counted-vmcnt pipeline, split-fp16
// 3-term MFMA, distance epilogue, double-atomic partial sum.
__global__ __launch_bounds__(256)
void pairsum_mfma(const char* __restrict__ blob, const float* __restrict__ norms,
                  const int* __restrict__ Y, double* __restrict__ gsum)
{
    // triangular decode: cum(b) = b*(129-b)/2
    const int kb = blockIdx.x;
    int bi = (int)((129.0f - sqrtf(fmaf(-8.0f, (float)kb, 129.0f * 129.0f))) * 0.5f);
    while ((bi + 1) * (129 - (bi + 1)) / 2 <= kb) ++bi;
    while (bi * (129 - bi) / 2 > kb) --bi;
    const int bj = bi + (kb - bi * (129 - bi) / 2);
    const int i0 = bi * BM, j0 = bj * BM;

    const int tid  = threadIdx.x;
    const int lane = tid & 63;
    const int w    = tid >> 6;        // wave 0..3
    const int wy   = w >> 1;          // 2x2 wave grid, 64x64 each
    const int wx   = w & 1;
    const int lr   = lane & 31;       // row/col within 32x32 MFMA tile
    const int lh   = lane >> 5;       // k-half selector

    // LDS: 2 buffers x (A-chunk 16KB + B-chunk 16KB) = 64KB, linear dest
    __shared__ __align__(16) char tile[65536];
    __shared__ float nI[BM], nJ[BM];
    __shared__ int   yI[BM], yJ[BM];
    __shared__ double wsum[4];

    if (tid < BM) { nI[tid] = norms[i0 + tid]; yI[tid] = Y[i0 + tid]; }
    else { const int r = tid & (BM - 1); nJ[r] = norms[j0 + r]; yJ[r] = Y[j0 + r]; }
    __syncthreads();   // full drain ONCE: vmcnt clean before counted pipeline

    const char* Ablob = blob + (size_t)bi * BLOB_PER_RB;
    const char* Bblob = blob + (size_t)bj * BLOB_PER_RB;

    // 8 async 16B loads per thread per phase: 4 for A-chunk, 4 for B-chunk
    auto STAGE = [&](int p, int s) {
        const char* gA = Ablob + p * BLOB_PER_PH + tid * 16;
        const char* gB = Bblob + p * BLOB_PER_PH + tid * 16;
        char* lA = tile + s * 32768 + tid * 16;
        #pragma unroll
        for (int q = 0; q < 4; ++q) {
            gload_lds16(gA + q * 4096, lA + q * 4096);
            gload_lds16(gB + q * 4096, lA + 16384 + q * 4096);
        }
    };

    f32x16 acc[2][2];
    #pragma unroll
    for (int m = 0; m < 2; ++m)
        #pragma unroll
        for (int n = 0; n < 2; ++n)
            #pragma unroll
            for (int r = 0; r < 16; ++r)
                acc[m][n][r] = 0.0f;

    STAGE(0, 0);
    STAGE(1, 1);   // 16 outstanding per thread

    #pragma unroll
    for (int p = 0; p < 4; ++p) {
        // wait own phase-p loads (keep next phase's 8 in flight), then barrier
        if (p < 3) asm volatile("s_waitcnt vmcnt(8)" ::: "memory");
        else       asm volatile("s_waitcnt vmcnt(0)" ::: "memory");
        __builtin_amdgcn_s_barrier();
        __builtin_amdgcn_sched_barrier(0);

        const char* Ab = tile + ((p & 1) ? 32768 : 0);
        const char* Bb = Ab + 16384;
        #pragma unroll
        for (int ks = 0; ks < 2; ++ks) {
            const int g = ks * 2 + lh;     // 16B hi-group within phase row
            half8 ah[2], al[2], bh[2], bl[2];
            #pragma unroll
            for (int m = 0; m < 2; ++m) {
                const int ar = wy * 64 + m * 32 + lr;
                const int ao = ar * 128 + (((g ^ (ar & 7))) << 4);
                ah[m] = *(const half8*)(Ab + ao);
                al[m] = *(const half8*)(Ab + (ao ^ 64));   // lo group = hi slot ^ 4<<4
                const int br = wx * 64 + m * 32 + lr;
                const int bo = br * 128 + (((g ^ (br & 7))) << 4);
                bh[m] = *(const half8*)(Bb + bo);
                bl[m] = *(const half8*)(Bb + (bo ^ 64));
            }
            #pragma unroll
            for (int m = 0; m < 2; ++m)
                #pragma unroll
                for (int n = 0; n < 2; ++n) {
                    acc[m][n] = __builtin_amdgcn_mfma_f32_32x32x16_f16(ah[m], bh[n], acc[m][n], 0, 0, 0);
                    acc[m][n] = __builtin_amdgcn_mfma_f32_32x32x16_f16(ah[m], bl[n], acc[m][n], 0, 0, 0);
                    acc[m][n] = __builtin_amdgcn_mfma_f32_32x32x16_f16(al[m], bh[n], acc[m][n], 0, 0, 0);
                }
        }

        __builtin_amdgcn_sched_barrier(0);
        __builtin_amdgcn_s_barrier();          // all waves done reading this buffer
        if (p + 2 < 4) STAGE(p + 2, p & 1);    // refill freed buffer
    }

    // epilogue: C/D map col=lane&31, row=(reg&3)+8*(reg>>2)+4*(lane>>5)
    float s = 0.0f;
    float nJv[2]; int yJv[2];
    #pragma unroll
    for (int n = 0; n < 2; ++n) {
        const int lj = wx * 64 + n * 32 + lr;
        nJv[n] = nJ[lj]; yJv[n] = yJ[lj];
    }
    #pragma unroll
    for (int m = 0; m < 2; ++m) {
        #pragma unroll
        for (int r = 0; r < 16; ++r) {
            const int rowin = (r & 3) + 8 * (r >> 2) + 4 * lh;
            const int li = wy * 64 + m * 32 + rowin;
            const float ni = nI[li];
            const int   yi = yI[li];
            const int   gi = i0 + li;
            #pragma unroll
            for (int n = 0; n < 2; ++n) {
                const int gj = j0 + wx * 64 + n * 32 + lr;
                float sq = fmaf(-2.0f, acc[m][n][r], ni + nJv[n]);
                sq = fmaxf(sq, 0.0f);
                const float d = __builtin_amdgcn_sqrtf(sq);
                if (gi < gj) s = fmaf((yi == yJv[n]) ? 1.0f : -0.5f, d, s);
            }
        }
    }

    #pragma unroll
    for (int off = 32; off > 0; off >>= 1) s += __shfl_down(s, off);
    if (lane == 0) wsum[w] = (double)s;
    __syncthreads();
    if (tid == 0) atomicAdd(gsum, wsum[0] + wsum[1] + wsum[2] + wsum[3]);
}

__global__ void finalize_kernel(const double* __restrict__ gsum, float* __restrict__ out)
{
    out[0] = (float)(2.0 * gsum[0]);
}

// ---------------------------------------------------------------------------
// Fallback (ws too small): round-1 VALU kernel, known-correct.
#define LDSPAD 4
#define LDB (BM + LDSPAD)
__global__ __launch_bounds__(256)
void pairsum_valu(const float* __restrict__ X, const int* __restrict__ Y,
                  double* __restrict__ gsum)
{
    const int bj = blockIdx.x, bi = blockIdx.y;
    if (bi > bj) return;
    const int tid = threadIdx.x;
    const int i0 = bi * BM, j0 = bj * BM;
    __shared__ float As[32][LDB], Bs[32][LDB];
    __shared__ float nI[BM], nJ[BM];
    __shared__ int yI[BM], yJ[BM];
    __shared__ double wsum[4];
    {
        const int r = tid & (BM - 1);
        const bool isJ = tid >= BM;
        const int row = (isJ ? j0 : i0) + r;
        const float4* p = (const float4*)(X + (size_t)row * DIM);
        float s = 0.f;
        #pragma unroll
        for (int q = 0; q < DIM / 4; ++q) {
            float4 v = p[q];
            s = fmaf(v.x, v.x, s); s = fmaf(v.y, v.y, s);
            s = fmaf(v.z, v.z, s); s = fmaf(v.w, v.w, s);
        }
        if (isJ) { nJ[r] = s; yJ[r] = Y[row]; }
        else     { nI[r] = s; yI[r] = Y[row]; }
    }
    float dot[8][8];
    #pragma unroll
    for (int m = 0; m < 8; ++m)
        #pragma unroll
        for (int n = 0; n < 8; ++n) dot[m][n] = 0.f;
    const int tx = tid & 15, ty = tid >> 4;
    for (int kc = 0; kc < DIM; kc += 32) {
        __syncthreads();
        #pragma unroll
        for (int p = 0; p < 4; ++p) {
            const int s2 = p * 256 + tid;
            const int row = s2 >> 3, kg = s2 & 7;
            const float4 va = *(const float4*)(X + (size_t)(i0 + row) * DIM + kc + kg * 4);
            const float4 vb = *(const float4*)(X + (size_t)(j0 + row) * DIM + kc + kg * 4);
            As[kg*4+0][row] = va.x; As[kg*4+1][row] = va.y;
            As[kg*4+2][row] = va.z; As[kg*4+3][row] = va.w;
            Bs[kg*4+0][row] = vb.x; Bs[kg*4+1][row] = vb.y;
            Bs[kg*4+2][row] = vb.z; Bs[kg*4+3][row] = vb.w;
        }
        __syncthreads();
        #pragma unroll
        for (int k = 0; k < 32; ++k) {
            float a[8], b[8];
            *(float4*)&a[0] = *(const float4*)&As[k][ty*8];
            *(float4*)&a[4] = *(const float4*)&As[k][ty*8+4];
            *(float4*)&b[0] = *(const float4*)&Bs[k][tx*8];
            *(float4*)&b[4] = *(const float4*)&Bs[k][tx*8+4];
            #pragma unroll
            for (int m = 0; m < 8; ++m)
                #pragma unroll
                for (int n = 0; n < 8; ++n)
                    dot[m][n] = fmaf(a[m], b[n], dot[m][n]);
        }
    }
    float s = 0.f;
    const int ib = ty * 8, jb = tx * 8;
    #pragma unroll
    for (int m = 0; m < 8; ++m) {
        const int gi = i0 + ib + m;
        const float ni = nI[ib + m];
        const int yi = yI[ib + m];
        #pragma unroll
        for (int n = 0; n < 8; ++n) {
            const int gj = j0 + jb + n;
            float sq = fmaf(-2.f, dot[m][n], ni + nJ[jb + n]);
            sq = fmaxf(sq, 0.f);
            const float d = __builtin_amdgcn_sqrtf(sq);
            if (gi < gj) s = fmaf((yi == yJ[jb + n]) ? 1.0f : -0.5f, d, s);
        }
    }
    #pragma unroll
    for (int off = 32; off > 0; off >>= 1) s += __shfl_down(s, off);
    const int lane = tid & 63, wid = tid >> 6;
    if (lane == 0) wsum[wid] = (double)s;
    __syncthreads();
    if (tid == 0) atomicAdd(gsum, wsum[0] + wsum[1] + wsum[2] + wsum[3]);
}

// ---------------------------------------------------------------------------
extern "C" void kernel_launch(void* const* d_in, const int* in_sizes, int n_in,
                              void* d_out, int out_size, void* d_ws, size_t ws_size,
                              hipStream_t stream)
{
    const float* X = (const float*)d_in[0];
    const int*   Y = (const int*)d_in[1];
    float* out = (float*)d_out;

    // ws layout: [0] double gsum | 64: blob 4MB | +4MB: norms 32KB
    const size_t OFF_BLOB = 64;
    const size_t OFF_NORM = OFF_BLOB + (size_t)NBLK * BLOB_PER_RB;
    const size_t REQ      = OFF_NORM + (size_t)N_ROWS * 4;

    double* gsum = (double*)d_ws;
    hipMemsetAsync(d_ws, 0, sizeof(double), stream);

    if (ws_size >= REQ) {
        char*  blob  = (char*)d_ws + OFF_BLOB;
        float* norms = (float*)((char*)d_ws + OFF_NORM);
        prep_tiled<<<(N_ROWS * 16) / 256, 256, 0, stream>>>(X, blob, norms);
        pairsum_mfma<<<NTRI, 256, 0, stream>>>(blob, norms, Y, gsum);
    } else {
        dim3 grid(NBLK, NBLK);
        pairsum_valu<<<grid, 256, 0, stream>>>(X, Y, gsum);
    }
    finalize_kernel<<<1, 1, 0, stream>>>(gsum, out);
}